// Round 5
// baseline (1529.751 us; speedup 1.0000x reference)
//
#include <hip/hip_runtime.h>

// HeteroGraphSage: 2-layer SAGEConv(mean) + PReLU + input-skip.
// N=100000, IN=D=64, E=1600000, fp32.
// CSR build (hist/scan/fill -> dst-sorted packed edges), then per-layer fused
// kernel. Phase A (gather): each wave vector-loads 64 packed edges (one
// coalesced 256B load, vmcnt path), broadcasts each via v_readlane (VALU,
// no lgkmcnt), does 1 coalesced feature load + 1 ds_add_f32 per edge.
// R4's scalar esort loads shared lgkmcnt with ds_add -> full LDS-queue drain
// per iteration (VALUBusy 9.8%); this removes all scalar loads from the loop.
// Phase B (dense): lane=node, wave owns 8 output dims, weight rows are
// wave-uniform -> scalar s_loads feeding v_fma.

#define BLOCK 512

__global__ __launch_bounds__(256) void hist_kernel(
    const int* __restrict__ dst, int* __restrict__ deg, int E)
{
    int i = blockIdx.x * blockDim.x + threadIdx.x;
    int stride = gridDim.x * blockDim.x;
    for (int e = i; e < E; e += stride) atomicAdd(&deg[dst[e]], 1);
}

__global__ __launch_bounds__(256) void bsum_kernel(
    const int* __restrict__ deg, int* __restrict__ bsum, int n)
{
    __shared__ int sh[256];
    int i = blockIdx.x * 256 + threadIdx.x;
    sh[threadIdx.x] = (i < n) ? deg[i] : 0;
    __syncthreads();
    for (int s = 128; s > 0; s >>= 1) {
        if (threadIdx.x < s) sh[threadIdx.x] += sh[threadIdx.x + s];
        __syncthreads();
    }
    if (threadIdx.x == 0) bsum[blockIdx.x] = sh[0];
}

__global__ __launch_bounds__(512) void scanb_kernel(
    const int* __restrict__ bsum, int* __restrict__ bsumX, int nb)
{
    __shared__ int sh[512];
    int tid = threadIdx.x;
    int v = (tid < nb) ? bsum[tid] : 0;
    sh[tid] = v;
    __syncthreads();
    for (int off = 1; off < 512; off <<= 1) {
        int t = (tid >= off) ? sh[tid - off] : 0;
        __syncthreads();
        sh[tid] += t;
        __syncthreads();
    }
    bsumX[tid] = sh[tid] - v;   // exclusive
}

// writes rowStart AND seeds cursor with the same value
__global__ __launch_bounds__(256) void rowstart_kernel(
    const int* __restrict__ deg, const int* __restrict__ bsumX,
    int* __restrict__ rowStart, int* __restrict__ cursor, int n)
{
    __shared__ int sh[256];
    int tid = threadIdx.x;
    int i = blockIdx.x * 256 + tid;
    int v = (i < n) ? deg[i] : 0;
    sh[tid] = v;
    __syncthreads();
    for (int off = 1; off < 256; off <<= 1) {
        int t = (tid >= off) ? sh[tid - off] : 0;
        __syncthreads();
        sh[tid] += t;
        __syncthreads();
    }
    if (i < n) {
        int rs = sh[tid] - v + bsumX[blockIdx.x];
        rowStart[i] = rs;
        cursor[i]   = rs;
    }
}

// esort[pos] = src | (dstLocal << 26)  (src < 2^26; dstLocal = dst & 63)
__global__ __launch_bounds__(256) void fill_kernel(
    const int* __restrict__ src, const int* __restrict__ dst,
    int* __restrict__ cursor, unsigned int* __restrict__ esort, int E)
{
    int i = blockIdx.x * blockDim.x + threadIdx.x;
    int stride = gridDim.x * blockDim.x;
    for (int e = i; e < E; e += stride) {
        int d = dst[e];
        int pos = atomicAdd(&cursor[d], 1);
        esort[pos] = (unsigned int)src[e] | ((unsigned int)(d & 63) << 26);
    }
}

// out = PReLU( mean_agg @ wl^T + bl + hin @ wr^T , a ) + x0 @ wskip^T + bskip
__global__ __launch_bounds__(BLOCK) void layer_kernel(
    const int* __restrict__ rowStart, const int* __restrict__ deg,
    const unsigned int* __restrict__ esort,
    const float* __restrict__ hin, const float* __restrict__ x0,
    const float* __restrict__ wl, const float* __restrict__ bl,
    const float* __restrict__ wr, const float* __restrict__ wskip,
    const float* __restrict__ bskip, const float* __restrict__ aprelu,
    float* __restrict__ out, int n, int E)
{
    // stride 65: dword idx = 65*r + c -> bank (r+c)%32. Phase A atomics
    // (r fixed, c=lane): 2-way = free. Phase B reads (r=lane, c fixed):
    // 2-way = free.
    __shared__ float agg_s[64 * 65];
    __shared__ float h_s[64 * 65];
    __shared__ float x_s[64 * 65];

    const int tid  = threadIdx.x;
    const int lane = tid & 63;
    const int wvu  = __builtin_amdgcn_readfirstlane(tid >> 6);  // 0..7

    const int tileBase = blockIdx.x * 64;
    const int tileEnd  = min(tileBase + 64, n);

    for (int i = tid; i < 64 * 65; i += BLOCK) agg_s[i] = 0.f;
    for (int i = tid; i < 64 * 64; i += BLOCK) {
        const int nl = i >> 6, d = i & 63;
        const int node = tileBase + nl;
        float hv = 0.f, xv = 0.f;
        if (node < n) {
            hv = hin[(size_t)node * 64 + d];
            xv = x0[(size_t)node * 64 + d];
        }
        h_s[nl * 65 + d] = hv;
        x_s[nl * 65 + d] = xv;
    }
    __syncthreads();

    // ---- Phase A: edge-parallel gather. Wave grabs 64 edges with ONE
    // coalesced vector load, then broadcasts each via v_readlane (no memory).
    const int eBeg = rowStart[tileBase];
    const int eEnd = (tileEnd < n) ? rowStart[tileEnd] : E;

    for (int base = eBeg + wvu * 64; base < eEnd; base += BLOCK) {
        const int cnt = min(64, eEnd - base);
        unsigned int p = 0u;
        if (lane < cnt) p = esort[base + lane];   // vector load, vmcnt
        if (cnt == 64) {
#pragma unroll 8
            for (int j = 0; j < 64; j++) {
                const unsigned int pj = __builtin_amdgcn_readlane(p, j);
                const float v = hin[(size_t)(pj & 0x03FFFFFFu) * 64 + lane];
                atomicAdd(&agg_s[(pj >> 26) * 65 + lane], v);
            }
        } else {
            for (int j = 0; j < cnt; j++) {
                const unsigned int pj = __builtin_amdgcn_readlane(p, j);
                const float v = hin[(size_t)(pj & 0x03FFFFFFu) * 64 + lane];
                atomicAdd(&agg_s[(pj >> 26) * 65 + lane], v);
            }
        }
    }
    __syncthreads();

    // ---- Phase B: dense. lane = node; this wave covers dims [wvu*8, wvu*8+8).
    const int node = tileBase + lane;
    const float dgf = (node < n) ? (float)deg[node] : 1.f;
    const float inv = 1.0f / fmaxf(dgf, 1.0f);

    float acc1[8], acc2[8], acc3[8];
#pragma unroll
    for (int dd = 0; dd < 8; dd++) { acc1[dd] = 0.f; acc2[dd] = 0.f; acc3[dd] = 0.f; }

    for (int kc = 0; kc < 8; kc++) {
        float ak[8], hk[8], xk[8];
#pragma unroll
        for (int k = 0; k < 8; k++) {
            ak[k] = agg_s[lane * 65 + kc * 8 + k];
            hk[k] = h_s[lane * 65 + kc * 8 + k];
            xk[k] = x_s[lane * 65 + kc * 8 + k];
        }
#pragma unroll
        for (int dd = 0; dd < 8; dd++) {
            const int d = wvu * 8 + dd;            // wave-uniform -> s_loads
            const float* wlr = wl    + d * 64 + kc * 8;
            const float* wrr = wr    + d * 64 + kc * 8;
            const float* wsr = wskip + d * 64 + kc * 8;
#pragma unroll
            for (int k = 0; k < 8; k++) {
                acc1[dd] += ak[k] * wlr[k];
                acc2[dd] += hk[k] * wrr[k];
                acc3[dd] += xk[k] * wsr[k];
            }
        }
    }
    __syncthreads();   // all waves done reading agg_s before alias-write

    float* out_s = agg_s;
#pragma unroll
    for (int dd = 0; dd < 8; dd++) {
        const int d = wvu * 8 + dd;
        float z = acc1[dd] * inv + acc2[dd] + bl[d];
        z = (z >= 0.f) ? z : aprelu[d] * z;
        out_s[lane * 65 + d] = z + acc3[dd] + bskip[d];
    }
    __syncthreads();

    for (int i = tid; i < 64 * 64; i += BLOCK) {
        const int nl = i >> 6, d = i & 63;
        const int nd = tileBase + nl;
        if (nd < n) out[(size_t)nd * 64 + d] = out_s[nl * 65 + d];
    }
}

extern "C" void kernel_launch(void* const* d_in, const int* in_sizes, int n_in,
                              void* d_out, int out_size, void* d_ws, size_t ws_size,
                              hipStream_t stream)
{
    const float* x   = (const float*)d_in[0];
    const int*   ei  = (const int*)d_in[1];
    const float* wl0 = (const float*)d_in[2];
    const float* bl0 = (const float*)d_in[3];
    const float* wr0 = (const float*)d_in[4];
    const float* ws0 = (const float*)d_in[5];
    const float* bs0 = (const float*)d_in[6];
    const float* a0  = (const float*)d_in[7];
    const float* wl1 = (const float*)d_in[8];
    const float* bl1 = (const float*)d_in[9];
    const float* wr1 = (const float*)d_in[10];
    const float* ws1 = (const float*)d_in[11];
    const float* bs1 = (const float*)d_in[12];
    const float* a1  = (const float*)d_in[13];

    const int n = in_sizes[0] / 64;
    const int E = in_sizes[1] / 2;
    const int* src = ei;
    const int* dst = ei + E;

    int* deg            = (int*)d_ws;
    int* cursor         = deg + n;
    int* rowStart       = cursor + n;
    int* bsum           = rowStart + n;
    int* bsumX          = bsum + 512;
    unsigned int* esort = (unsigned int*)(bsumX + 512);
    float* h1           = (float*)(esort + E);

    hipMemsetAsync(deg, 0, (size_t)n * sizeof(int), stream);

    const int nb = (n + 255) / 256;   // 391 <= 512

    hist_kernel<<<2048, 256, 0, stream>>>(dst, deg, E);
    bsum_kernel<<<nb, 256, 0, stream>>>(deg, bsum, n);
    scanb_kernel<<<1, 512, 0, stream>>>(bsum, bsumX, nb);
    rowstart_kernel<<<nb, 256, 0, stream>>>(deg, bsumX, rowStart, cursor, n);
    fill_kernel<<<2048, 256, 0, stream>>>(src, dst, cursor, esort, E);

    const int ntiles = (n + 63) / 64;

    layer_kernel<<<ntiles, BLOCK, 0, stream>>>(rowStart, deg, esort,
        x, x, wl0, bl0, wr0, ws0, bs0, a0, h1, n, E);
    layer_kernel<<<ntiles, BLOCK, 0, stream>>>(rowStart, deg, esort,
        h1, x, wl1, bl1, wr1, ws1, bs1, a1, (float*)d_out, n, E);
}

// Round 6
// 839.470 us; speedup vs baseline: 1.8223x; 1.8223x over previous
//
#include <hip/hip_runtime.h>

// HeteroGraphSage: 2-layer SAGEConv(mean) + PReLU + input-skip.
// N=100000, IN=D=64, E=1600000, fp32.
// CSR build (hist/scan/fill -> dst-sorted packed edges), then per-layer fused
// kernel. Phase A (gather): NO LDS atomics (R4/R5 showed ds_add_f32 costs
// ~243 cyc/op serialized per CU = the 633us wall). Edges are dst-sorted, so
// each wave OWNS 8 nodes of the 64-node tile and walks their contiguous edge
// runs with a register accumulator (lane=feature), flushing each node once
// via plain ds_write. Phase B (dense): lane=node, wave owns 8 output dims,
// wave-uniform weight rows -> scalar loads feeding v_fma.

#define BLOCK 512

__global__ __launch_bounds__(256) void hist_kernel(
    const int* __restrict__ dst, int* __restrict__ deg, int E)
{
    int i = blockIdx.x * blockDim.x + threadIdx.x;
    int stride = gridDim.x * blockDim.x;
    for (int e = i; e < E; e += stride) atomicAdd(&deg[dst[e]], 1);
}

__global__ __launch_bounds__(256) void bsum_kernel(
    const int* __restrict__ deg, int* __restrict__ bsum, int n)
{
    __shared__ int sh[256];
    int i = blockIdx.x * 256 + threadIdx.x;
    sh[threadIdx.x] = (i < n) ? deg[i] : 0;
    __syncthreads();
    for (int s = 128; s > 0; s >>= 1) {
        if (threadIdx.x < s) sh[threadIdx.x] += sh[threadIdx.x + s];
        __syncthreads();
    }
    if (threadIdx.x == 0) bsum[blockIdx.x] = sh[0];
}

__global__ __launch_bounds__(512) void scanb_kernel(
    const int* __restrict__ bsum, int* __restrict__ bsumX, int nb)
{
    __shared__ int sh[512];
    int tid = threadIdx.x;
    int v = (tid < nb) ? bsum[tid] : 0;
    sh[tid] = v;
    __syncthreads();
    for (int off = 1; off < 512; off <<= 1) {
        int t = (tid >= off) ? sh[tid - off] : 0;
        __syncthreads();
        sh[tid] += t;
        __syncthreads();
    }
    bsumX[tid] = sh[tid] - v;   // exclusive
}

// writes rowStart AND seeds cursor with the same value
__global__ __launch_bounds__(256) void rowstart_kernel(
    const int* __restrict__ deg, const int* __restrict__ bsumX,
    int* __restrict__ rowStart, int* __restrict__ cursor, int n)
{
    __shared__ int sh[256];
    int tid = threadIdx.x;
    int i = blockIdx.x * 256 + tid;
    int v = (i < n) ? deg[i] : 0;
    sh[tid] = v;
    __syncthreads();
    for (int off = 1; off < 256; off <<= 1) {
        int t = (tid >= off) ? sh[tid - off] : 0;
        __syncthreads();
        sh[tid] += t;
        __syncthreads();
    }
    if (i < n) {
        int rs = sh[tid] - v + bsumX[blockIdx.x];
        rowStart[i] = rs;
        cursor[i]   = rs;
    }
}

// esort[pos] = src | (dstLocal << 26)  (src < 2^26; dstLocal = dst & 63)
__global__ __launch_bounds__(256) void fill_kernel(
    const int* __restrict__ src, const int* __restrict__ dst,
    int* __restrict__ cursor, unsigned int* __restrict__ esort, int E)
{
    int i = blockIdx.x * blockDim.x + threadIdx.x;
    int stride = gridDim.x * blockDim.x;
    for (int e = i; e < E; e += stride) {
        int d = dst[e];
        int pos = atomicAdd(&cursor[d], 1);
        esort[pos] = (unsigned int)src[e] | ((unsigned int)(d & 63) << 26);
    }
}

// out = PReLU( mean_agg @ wl^T + bl + hin @ wr^T , a ) + x0 @ wskip^T + bskip
__global__ __launch_bounds__(BLOCK) void layer_kernel(
    const int* __restrict__ rowStart, const int* __restrict__ deg,
    const unsigned int* __restrict__ esort,
    const float* __restrict__ hin, const float* __restrict__ x0,
    const float* __restrict__ wl, const float* __restrict__ bl,
    const float* __restrict__ wr, const float* __restrict__ wskip,
    const float* __restrict__ bskip, const float* __restrict__ aprelu,
    float* __restrict__ out, int n, int E)
{
    // stride 65: dword idx = 65*r + c -> bank (r+c)%32; row access (r fixed,
    // c=lane) and column access (r=lane, c fixed) are both 2-way = free.
    __shared__ float agg_s[64 * 65];
    __shared__ float h_s[64 * 65];
    __shared__ float x_s[64 * 65];

    const int tid  = threadIdx.x;
    const int lane = tid & 63;
    const int wvu  = __builtin_amdgcn_readfirstlane(tid >> 6);  // 0..7

    const int tileBase = blockIdx.x * 64;
    const int tileEnd  = min(tileBase + 64, n);

    for (int i = tid; i < 64 * 65; i += BLOCK) agg_s[i] = 0.f;
    for (int i = tid; i < 64 * 64; i += BLOCK) {
        const int nl = i >> 6, d = i & 63;
        const int node = tileBase + nl;
        float hv = 0.f, xv = 0.f;
        if (node < n) {
            hv = hin[(size_t)node * 64 + d];
            xv = x0[(size_t)node * 64 + d];
        }
        h_s[nl * 65 + d] = hv;
        x_s[nl * 65 + d] = xv;
    }

    // ---- Phase A: wave owns nodes [tileBase+wvu*8, +8). Register acc
    // (lane=feature) over each node's contiguous dst-sorted edge run; one
    // plain ds_write per node. No atomics anywhere.
    const int n0 = min(tileBase + wvu * 8, tileEnd);
    const int n1 = min(n0 + 8, tileEnd);

    for (int nd = n0; nd < n1; nd++) {
        const int rs = rowStart[nd];
        const int dg = deg[nd];
        float acc = 0.f;
        int pos = rs, rem = dg;
        while (rem > 0) {
            const int cnt = min(64, rem);
            unsigned int p = 0u;
            if (lane < cnt) p = esort[pos + lane];   // one coalesced load
#pragma unroll 8
            for (int j = 0; j < cnt; j++) {
                const unsigned int pj = __builtin_amdgcn_readlane(p, j);
                acc += hin[(size_t)(pj & 0x03FFFFFFu) * 64 + lane];
            }
            pos += cnt; rem -= cnt;
        }
        const float inv = 1.0f / fmaxf((float)dg, 1.0f);
        agg_s[(nd - tileBase) * 65 + lane] = acc * inv;   // mean folded here
    }
    __syncthreads();

    // ---- Phase B: dense. lane = node; this wave covers dims [wvu*8, wvu*8+8).
    float acc1[8], acc2[8], acc3[8];
#pragma unroll
    for (int dd = 0; dd < 8; dd++) { acc1[dd] = 0.f; acc2[dd] = 0.f; acc3[dd] = 0.f; }

    for (int kc = 0; kc < 8; kc++) {
        float ak[8], hk[8], xk[8];
#pragma unroll
        for (int k = 0; k < 8; k++) {
            ak[k] = agg_s[lane * 65 + kc * 8 + k];
            hk[k] = h_s[lane * 65 + kc * 8 + k];
            xk[k] = x_s[lane * 65 + kc * 8 + k];
        }
#pragma unroll
        for (int dd = 0; dd < 8; dd++) {
            const int d = wvu * 8 + dd;            // wave-uniform -> s_loads
            const float* wlr = wl    + d * 64 + kc * 8;
            const float* wrr = wr    + d * 64 + kc * 8;
            const float* wsr = wskip + d * 64 + kc * 8;
#pragma unroll
            for (int k = 0; k < 8; k++) {
                acc1[dd] += ak[k] * wlr[k];
                acc2[dd] += hk[k] * wrr[k];
                acc3[dd] += xk[k] * wsr[k];
            }
        }
    }
    __syncthreads();   // all waves done reading agg_s before alias-write

    float* out_s = agg_s;
#pragma unroll
    for (int dd = 0; dd < 8; dd++) {
        const int d = wvu * 8 + dd;
        float z = acc1[dd] + acc2[dd] + bl[d];
        z = (z >= 0.f) ? z : aprelu[d] * z;
        out_s[lane * 65 + d] = z + acc3[dd] + bskip[d];
    }
    __syncthreads();

    for (int i = tid; i < 64 * 64; i += BLOCK) {
        const int nl = i >> 6, d = i & 63;
        const int nd = tileBase + nl;
        if (nd < n) out[(size_t)nd * 64 + d] = out_s[nl * 65 + d];
    }
}

extern "C" void kernel_launch(void* const* d_in, const int* in_sizes, int n_in,
                              void* d_out, int out_size, void* d_ws, size_t ws_size,
                              hipStream_t stream)
{
    const float* x   = (const float*)d_in[0];
    const int*   ei  = (const int*)d_in[1];
    const float* wl0 = (const float*)d_in[2];
    const float* bl0 = (const float*)d_in[3];
    const float* wr0 = (const float*)d_in[4];
    const float* ws0 = (const float*)d_in[5];
    const float* bs0 = (const float*)d_in[6];
    const float* a0  = (const float*)d_in[7];
    const float* wl1 = (const float*)d_in[8];
    const float* bl1 = (const float*)d_in[9];
    const float* wr1 = (const float*)d_in[10];
    const float* ws1 = (const float*)d_in[11];
    const float* bs1 = (const float*)d_in[12];
    const float* a1  = (const float*)d_in[13];

    const int n = in_sizes[0] / 64;
    const int E = in_sizes[1] / 2;
    const int* src = ei;
    const int* dst = ei + E;

    int* deg            = (int*)d_ws;
    int* cursor         = deg + n;
    int* rowStart       = cursor + n;
    int* bsum           = rowStart + n;
    int* bsumX          = bsum + 512;
    unsigned int* esort = (unsigned int*)(bsumX + 512);
    float* h1           = (float*)(esort + E);

    hipMemsetAsync(deg, 0, (size_t)n * sizeof(int), stream);

    const int nb = (n + 255) / 256;   // 391 <= 512

    hist_kernel<<<2048, 256, 0, stream>>>(dst, deg, E);
    bsum_kernel<<<nb, 256, 0, stream>>>(deg, bsum, n);
    scanb_kernel<<<1, 512, 0, stream>>>(bsum, bsumX, nb);
    rowstart_kernel<<<nb, 256, 0, stream>>>(deg, bsumX, rowStart, cursor, n);
    fill_kernel<<<2048, 256, 0, stream>>>(src, dst, cursor, esort, E);

    const int ntiles = (n + 63) / 64;

    layer_kernel<<<ntiles, BLOCK, 0, stream>>>(rowStart, deg, esort,
        x, x, wl0, bl0, wr0, ws0, bs0, a0, h1, n, E);
    layer_kernel<<<ntiles, BLOCK, 0, stream>>>(rowStart, deg, esort,
        h1, x, wl1, bl1, wr1, ws1, bs1, a1, (float*)d_out, n, E);
}

// Round 7
// 612.393 us; speedup vs baseline: 2.4980x; 1.3708x over previous
//
#include <hip/hip_runtime.h>

// HeteroGraphSage: 2-layer SAGEConv(mean) + PReLU + input-skip.
// N=100000, IN=D=64, E=1600000, fp32. Mean degree = 16.
// CSR build (hist/scan/fill -> dst-sorted src list), then per-layer fused
// kernel. Phase A (gather): wave owns 8 nodes, processes them CONCURRENTLY:
// preload <=64 edge words per node (sentinel 0xFFFFFFFF past deg), then a
// depth loop issuing 8 independent scalar-base loads per iteration (sentinel
// -> zero row => branch-free). R6's per-node serial walk was latency-bound
// (~108 cyc/edge, VALUBusy 25%); this puts 8-16 loads in flight per wave.
// Phase B (dense): lane=node, wave owns 8 output dims, wave-uniform weight
// rows -> scalar loads feeding v_fma.

#define BLOCK 512

__global__ __launch_bounds__(256) void hist_kernel(
    const int* __restrict__ dst, int* __restrict__ deg, int E)
{
    int i = blockIdx.x * blockDim.x + threadIdx.x;
    int stride = gridDim.x * blockDim.x;
    for (int e = i; e < E; e += stride) atomicAdd(&deg[dst[e]], 1);
}

__global__ __launch_bounds__(256) void bsum_kernel(
    const int* __restrict__ deg, int* __restrict__ bsum, int n)
{
    __shared__ int sh[256];
    int i = blockIdx.x * 256 + threadIdx.x;
    sh[threadIdx.x] = (i < n) ? deg[i] : 0;
    __syncthreads();
    for (int s = 128; s > 0; s >>= 1) {
        if (threadIdx.x < s) sh[threadIdx.x] += sh[threadIdx.x + s];
        __syncthreads();
    }
    if (threadIdx.x == 0) bsum[blockIdx.x] = sh[0];
}

__global__ __launch_bounds__(512) void scanb_kernel(
    const int* __restrict__ bsum, int* __restrict__ bsumX, int nb)
{
    __shared__ int sh[512];
    int tid = threadIdx.x;
    int v = (tid < nb) ? bsum[tid] : 0;
    sh[tid] = v;
    __syncthreads();
    for (int off = 1; off < 512; off <<= 1) {
        int t = (tid >= off) ? sh[tid - off] : 0;
        __syncthreads();
        sh[tid] += t;
        __syncthreads();
    }
    bsumX[tid] = sh[tid] - v;   // exclusive
}

// writes rowStart AND seeds cursor with the same value
__global__ __launch_bounds__(256) void rowstart_kernel(
    const int* __restrict__ deg, const int* __restrict__ bsumX,
    int* __restrict__ rowStart, int* __restrict__ cursor, int n)
{
    __shared__ int sh[256];
    int tid = threadIdx.x;
    int i = blockIdx.x * 256 + tid;
    int v = (i < n) ? deg[i] : 0;
    sh[tid] = v;
    __syncthreads();
    for (int off = 1; off < 256; off <<= 1) {
        int t = (tid >= off) ? sh[tid - off] : 0;
        __syncthreads();
        sh[tid] += t;
        __syncthreads();
    }
    if (i < n) {
        int rs = sh[tid] - v + bsumX[blockIdx.x];
        rowStart[i] = rs;
        cursor[i]   = rs;
    }
}

// esort[pos] = src (plain; ownership in layer_kernel implies dst)
__global__ __launch_bounds__(256) void fill_kernel(
    const int* __restrict__ src, const int* __restrict__ dst,
    int* __restrict__ cursor, unsigned int* __restrict__ esort, int E)
{
    int i = blockIdx.x * blockDim.x + threadIdx.x;
    int stride = gridDim.x * blockDim.x;
    for (int e = i; e < E; e += stride) {
        int d = dst[e];
        int pos = atomicAdd(&cursor[d], 1);
        esort[pos] = (unsigned int)src[e];
    }
}

#define SENT 0xFFFFFFFFu

// out = PReLU( mean_agg @ wl^T + bl + hin @ wr^T , a ) + x0 @ wskip^T + bskip
__global__ __launch_bounds__(BLOCK) void layer_kernel(
    const int* __restrict__ rowStart, const int* __restrict__ deg,
    const unsigned int* __restrict__ esort,
    const float* __restrict__ hin, const float* __restrict__ x0,
    const float* __restrict__ zrow,
    const float* __restrict__ wl, const float* __restrict__ bl,
    const float* __restrict__ wr, const float* __restrict__ wskip,
    const float* __restrict__ bskip, const float* __restrict__ aprelu,
    float* __restrict__ out, int n, int E)
{
    // stride 65: dword idx = 65*r + c -> bank (r+c)%32; row and column access
    // patterns are both worst-case 2-way = free.
    __shared__ float agg_s[64 * 65];
    __shared__ float h_s[64 * 65];
    __shared__ float x_s[64 * 65];

    const int tid  = threadIdx.x;
    const int lane = tid & 63;
    const int wvu  = __builtin_amdgcn_readfirstlane(tid >> 6);  // 0..7

    const int tileBase = blockIdx.x * 64;
    const int tileEnd  = min(tileBase + 64, n);

    for (int i = tid; i < 64 * 64; i += BLOCK) {
        const int nl = i >> 6, d = i & 63;
        const int node = tileBase + nl;
        float hv = 0.f, xv = 0.f;
        if (node < n) {
            hv = hin[(size_t)node * 64 + d];
            xv = x0[(size_t)node * 64 + d];
        }
        h_s[nl * 65 + d] = hv;
        x_s[nl * 65 + d] = xv;
    }

    // ---- Phase A: wave owns nodes n0..n0+7, processed CONCURRENTLY.
    const int n0 = tileBase + wvu * 8;
    int rs_k[8], dg_k[8];
#pragma unroll
    for (int k = 0; k < 8; k++) {
        const int nd = n0 + k;
        const bool v = nd < tileEnd;
        rs_k[k] = v ? rowStart[nd] : 0;   // wave-uniform -> s_load
        dg_k[k] = v ? deg[nd] : 0;
    }

    unsigned int ew[8];
#pragma unroll
    for (int k = 0; k < 8; k++) {
        unsigned int w = SENT;
        if (lane < dg_k[k]) w = esort[rs_k[k] + lane];
        ew[k] = w;
    }

    float acc[8];
#pragma unroll
    for (int k = 0; k < 8; k++) acc[k] = 0.f;

    int mx = 0;
#pragma unroll
    for (int k = 0; k < 8; k++) mx = max(mx, min(dg_k[k], 64));

    for (int j = 0; j < mx; j++) {
#pragma unroll
        for (int k = 0; k < 8; k++) {
            const unsigned int s =
                (unsigned int)__builtin_amdgcn_readlane((int)ew[k], j);
            // wave-uniform base select: sentinel -> zero row (L1-hot, +0)
            const float* bp = (s == SENT) ? zrow : (hin + (size_t)s * 64);
            acc[k] += bp[lane];   // scalar-base + lane*4 load, independent
        }
    }

    // rare tail: deg > 64 (Poisson(16) => ~never, but must be correct)
#pragma unroll
    for (int k = 0; k < 8; k++) {
        if (dg_k[k] > 64) {
            int pos = rs_k[k] + 64, rem = dg_k[k] - 64;
            while (rem > 0) {
                const int cnt = min(64, rem);
                unsigned int w = 0u;
                if (lane < cnt) w = esort[pos + lane];
                for (int j = 0; j < cnt; j++) {
                    const unsigned int s =
                        (unsigned int)__builtin_amdgcn_readlane((int)w, j);
                    acc[k] += hin[(size_t)s * 64 + lane];
                }
                pos += cnt; rem -= cnt;
            }
        }
    }

#pragma unroll
    for (int k = 0; k < 8; k++) {
        const int nd = n0 + k;
        if (nd < tileEnd) {
            const float inv = 1.0f / fmaxf((float)dg_k[k], 1.0f);
            agg_s[(nd - tileBase) * 65 + lane] = acc[k] * inv;
        }
    }
    __syncthreads();

    // ---- Phase B: dense. lane = node; this wave covers dims [wvu*8, wvu*8+8).
    float acc1[8], acc2[8], acc3[8];
#pragma unroll
    for (int dd = 0; dd < 8; dd++) { acc1[dd] = 0.f; acc2[dd] = 0.f; acc3[dd] = 0.f; }

    for (int kc = 0; kc < 8; kc++) {
        float ak[8], hk[8], xk[8];
#pragma unroll
        for (int k = 0; k < 8; k++) {
            ak[k] = agg_s[lane * 65 + kc * 8 + k];
            hk[k] = h_s[lane * 65 + kc * 8 + k];
            xk[k] = x_s[lane * 65 + kc * 8 + k];
        }
#pragma unroll
        for (int dd = 0; dd < 8; dd++) {
            const int d = wvu * 8 + dd;            // wave-uniform -> s_loads
            const float* wlr = wl    + d * 64 + kc * 8;
            const float* wrr = wr    + d * 64 + kc * 8;
            const float* wsr = wskip + d * 64 + kc * 8;
#pragma unroll
            for (int k = 0; k < 8; k++) {
                acc1[dd] += ak[k] * wlr[k];
                acc2[dd] += hk[k] * wrr[k];
                acc3[dd] += xk[k] * wsr[k];
            }
        }
    }
    __syncthreads();   // all waves done reading agg_s before alias-write

    float* out_s = agg_s;
#pragma unroll
    for (int dd = 0; dd < 8; dd++) {
        const int d = wvu * 8 + dd;
        float z = acc1[dd] + acc2[dd] + bl[d];
        z = (z >= 0.f) ? z : aprelu[d] * z;
        out_s[lane * 65 + d] = z + acc3[dd] + bskip[d];
    }
    __syncthreads();

    for (int i = tid; i < 64 * 64; i += BLOCK) {
        const int nl = i >> 6, d = i & 63;
        const int nd = tileBase + nl;
        if (nd < n) out[(size_t)nd * 64 + d] = out_s[nl * 65 + d];
    }
}

extern "C" void kernel_launch(void* const* d_in, const int* in_sizes, int n_in,
                              void* d_out, int out_size, void* d_ws, size_t ws_size,
                              hipStream_t stream)
{
    const float* x   = (const float*)d_in[0];
    const int*   ei  = (const int*)d_in[1];
    const float* wl0 = (const float*)d_in[2];
    const float* bl0 = (const float*)d_in[3];
    const float* wr0 = (const float*)d_in[4];
    const float* ws0 = (const float*)d_in[5];
    const float* bs0 = (const float*)d_in[6];
    const float* a0  = (const float*)d_in[7];
    const float* wl1 = (const float*)d_in[8];
    const float* bl1 = (const float*)d_in[9];
    const float* wr1 = (const float*)d_in[10];
    const float* ws1 = (const float*)d_in[11];
    const float* bs1 = (const float*)d_in[12];
    const float* a1  = (const float*)d_in[13];

    const int n = in_sizes[0] / 64;
    const int E = in_sizes[1] / 2;
    const int* src = ei;
    const int* dst = ei + E;

    int* deg            = (int*)d_ws;
    int* cursor         = deg + n;
    int* rowStart       = cursor + n;
    int* bsum           = rowStart + n;
    int* bsumX          = bsum + 512;
    unsigned int* esort = (unsigned int*)(bsumX + 512);
    float* zrow         = (float*)(esort + E + 64);  // +64 pad: masked preload
                                                     // may touch up to E+63
    float* h1           = zrow + 64;

    hipMemsetAsync(deg, 0, (size_t)n * sizeof(int), stream);
    hipMemsetAsync(zrow, 0, 64 * sizeof(float), stream);

    const int nb = (n + 255) / 256;   // 391 <= 512

    hist_kernel<<<2048, 256, 0, stream>>>(dst, deg, E);
    bsum_kernel<<<nb, 256, 0, stream>>>(deg, bsum, n);
    scanb_kernel<<<1, 512, 0, stream>>>(bsum, bsumX, nb);
    rowstart_kernel<<<nb, 256, 0, stream>>>(deg, bsumX, rowStart, cursor, n);
    fill_kernel<<<2048, 256, 0, stream>>>(src, dst, cursor, esort, E);

    const int ntiles = (n + 63) / 64;

    layer_kernel<<<ntiles, BLOCK, 0, stream>>>(rowStart, deg, esort,
        x, x, zrow, wl0, bl0, wr0, ws0, bs0, a0, h1, n, E);
    layer_kernel<<<ntiles, BLOCK, 0, stream>>>(rowStart, deg, esort,
        h1, x, zrow, wl1, bl1, wr1, ws1, bs1, a1, (float*)d_out, n, E);
}